// Round 5
// baseline (240.404 us; speedup 1.0000x reference)
//
#include <hip/hip_runtime.h>

// Mandelbrot counts — R6-proven bit-exact arithmetic + compaction + wave-
// aggregated enqueue (R8) + packed 2px/lane (R12) + fat-reduced asm body and
// 3-dispatch pipeline (R13).
//
// R12 post-mortem: A went 110->83us but VALU accounting shows ~535 instr/lane
// vs ~270 ideal — ~2x mov/insert fat from single-op "=v" asm blocks
// (loop-carried zr/zi copies, pair-subreg act/cnt inserts). Also, dispatch
// budget: R8 already implied >=15us gap per dispatch boundary; R12 ran FIVE
// dispatches (zero + A + 3 strips) ~ 60us of gaps, and the strip ladder's
// algorithmic saving (~255M checks) was cancelled by 2 extra gaps vs a
// single packed fixed-240 B.
//
// R13: (1) fat-reduced packed check: two multi-instr asm blocks with "+v"
// in-place zr/zi (no loop-carried movs), "=&v" scratch, SCALAR act0/1 cnt0/1
// (cmp/cndmask/add, no subreg inserts) -> exactly 14 VALU per check-pair.
// (2) 3 dispatches: zero_ctrs + A_pk + single fixed-240 B_pk (2 recs/lane,
// paired k, k+half for coalescing). Single queue, seg_cap doubled.
//
// Exactness: per half, ops are v_pk_{mul,fma,add}_f32 == scalar v_{mul,fma,
// add}_f32 rounding; -zi2 via sign-bit xor == HW neg modifier (proven);
// sticky escape (mag<4)?act:0 NaN-safe; cnt+=act exact small-int add.
// absmax=0 lineage R6..R12. Cardioid/bulb shortcut margin 1e-3 (HW-valid).
//
// d_ws: [0,4096) 64 counter lines (64B apart, dword +0 used) | q float4 recs
// seg-major | int idx after. Overflow -> finish inline (correct, slower).
// Tiny ws -> proven scalar fallbacks.

#define MAX_ITERS 256

typedef __attribute__((ext_vector_type(2))) float f32x2;

// ---------- scalar proven body (fallback paths + overflow inline) ----------
__device__ __forceinline__ float mul32(float a, float b) {
    float d; asm("v_mul_f32 %0, %1, %2" : "=v"(d) : "v"(a), "v"(b)); return d;
}
__device__ __forceinline__ float add32(float a, float b) {
    float d; asm("v_add_f32 %0, %1, %2" : "=v"(d) : "v"(a), "v"(b)); return d;
}
__device__ __forceinline__ float fma32(float a, float b, float c) {
    float d; asm("v_fma_f32 %0, %1, %2, %3" : "=v"(d) : "v"(a), "v"(b), "v"(c)); return d;
}
__device__ __forceinline__ float fma32_negc(float a, float b, float c) {
    float d; asm("v_fma_f32 %0, %1, %2, -%3" : "=v"(d) : "v"(a), "v"(b), "v"(c)); return d;
}

__device__ __forceinline__ void iter_checks(float cr, float ci,
                                            float& zr, float& zi,
                                            float& act, float& cnt, int nchecks)
{
    #pragma unroll 8
    for (int s = 0; s < nchecks; ++s) {
        const float zi2 = mul32(zi, zi);
        const float mag = fma32(zr, zr, zi2);
        act = (mag < 4.0f) ? act : 0.0f;
        cnt = cnt + act;
        const float t   = fma32_negc(zr, zr, zi2);
        const float nr  = add32(t, cr);
        const float t2  = add32(zr, zr);
        zi = fma32(t2, zi, ci);
        zr = nr;
    }
}

// ---------- fat-reduced packed check: 14 VALU per 2 pixels ----------
__device__ __forceinline__ void check_pk(const f32x2 cr, const f32x2 ci,
                                         f32x2& zr, f32x2& zi,
                                         float& act0, float& act1,
                                         float& cnt0, float& cnt1)
{
    f32x2 zi2, mag, t, t2;
    // zi2 = fl(zi*zi); mag = fma(zr,zr,zi2)
    asm("v_pk_mul_f32 %0, %2, %2\n\t"
        "v_pk_fma_f32 %1, %3, %3, %0"
        : "=&v"(zi2), "=&v"(mag)
        : "v"(zi), "v"(zr));
    const f32x2 mzi2 = -zi2;   // sign-bit xor, exact (== HW neg modifier)
    // t = fma(zr,zr,-zi2); t2 = fl(zr+zr); zr' = fl(t+cr); zi' = fma(t2,zi,ci)
    asm("v_pk_fma_f32 %0, %2, %2, %4\n\t"
        "v_pk_add_f32 %1, %2, %2\n\t"
        "v_pk_add_f32 %2, %0, %5\n\t"
        "v_pk_fma_f32 %3, %1, %3, %6"
        : "=&v"(t), "=&v"(t2), "+v"(zr), "+v"(zi)
        : "v"(mzi2), "v"(cr), "v"(ci));
    act0 = (mag.x < 4.0f) ? act0 : 0.0f;   // sticky escape, NaN-safe
    act1 = (mag.y < 4.0f) ? act1 : 0.0f;
    cnt0 += act0;                          // exact small-int add
    cnt1 += act1;
}

__device__ __forceinline__ void iter_checks_pk(const f32x2 cr, const f32x2 ci,
                                               f32x2& zr, f32x2& zi,
                                               float& act0, float& act1,
                                               float& cnt0, float& cnt1,
                                               int nchecks)
{
    #pragma unroll 8
    for (int s = 0; s < nchecks; ++s)
        check_pk(cr, ci, zr, zi, act0, act1, cnt0, cnt1);
}

__device__ __forceinline__ int lane_id() {
    return __builtin_amdgcn_mbcnt_hi(~0u, __builtin_amdgcn_mbcnt_lo(~0u, 0));
}

__device__ __forceinline__ bool in_shortcut(float cr, float ci) {
    const float xq = cr - 0.25f;
    const float q  = xq * xq + ci * ci;
    const bool in_card = (q * (q + xq) - 0.25f * ci * ci) < -1e-3f;
    const float xb = cr + 1.0f;
    const bool in_bulb = (xb * xb + ci * ci) < (0.0625f - 1e-3f);
    return in_card | in_bulb;
}

__global__ void zero_ctrs(unsigned char* ws) {
    if (threadIdx.x < 64)
        *(unsigned*)(ws + (size_t)threadIdx.x * 64u) = 0u;
}

// ---------- stage A, packed: 2 pixels per thread ----------
__global__ __launch_bounds__(256) void mandel_stage_a_pk(
    const float* __restrict__ c_real, const float* __restrict__ c_imag,
    float* __restrict__ out, unsigned char* __restrict__ ws,
    unsigned seg_cap, int n)
{
    const int tp = blockIdx.x * blockDim.x + threadIdx.x;
    const int p0 = tp << 1;
    if (p0 >= n) return;
    const bool has1 = (p0 + 1) < n;

    f32x2 cr, ci;
    if (has1) {
        cr = *(const f32x2*)(c_real + p0);
        ci = *(const f32x2*)(c_imag + p0);
    } else {
        cr.x = c_real[p0]; cr.y = 0.0f;
        ci.x = c_imag[p0]; ci.y = 0.0f;
    }
    const bool sc0 = in_shortcut(cr.x, ci.x);
    const bool sc1 = in_shortcut(cr.y, ci.y);

    f32x2 zr = cr, zi = ci;
    float act0 = 1.0f, act1 = has1 ? 1.0f : 0.0f;
    float cnt0 = 0.0f, cnt1 = 0.0f;
    iter_checks_pk(cr, ci, zr, zi, act0, act1, cnt0, cnt1, 16); // z_0..z_15

    const bool s0 = (!sc0) && (act0 != 0.0f);
    const bool s1 = has1 && (!sc1) && (act1 != 0.0f);

    const unsigned long long m0 = __ballot(s0);
    const unsigned long long m1 = __ballot(s1);
    if ((m0 | m1) != 0ull) {
        const int lane = lane_id();
        const int leader = (int)__ffsll(m0 | m1) - 1;
        const int seg = blockIdx.x & 63;
        unsigned* ctr = (unsigned*)(ws + (size_t)seg * 64u);
        unsigned base = 0u;
        if (lane == leader)
            base = atomicAdd(ctr, (unsigned)(__popcll(m0) + __popcll(m1)));
        base = (unsigned)__shfl((int)base, leader, 64);
        float4* qf = (float4*)(ws + 4096);
        int*    qi = (int*)(ws + 4096 + (size_t)seg_cap * 64u * 16u);
        if (s0) {
            const unsigned slot = base +
                (unsigned)__popcll(m0 & ((1ull << lane) - 1ull));
            if (slot < seg_cap) {
                const size_t p = (size_t)seg * seg_cap + slot;
                qf[p] = make_float4(zr.x, zi.x, cr.x, ci.x);
                qi[p] = p0;
            } else {
                float zrs = zr.x, zis = zi.x, as = 1.0f, cs = cnt0;
                iter_checks(cr.x, ci.x, zrs, zis, as, cs, 240);
                out[p0] = cs;
            }
        }
        if (s1) {
            const unsigned slot = base + (unsigned)__popcll(m0) +
                (unsigned)__popcll(m1 & ((1ull << lane) - 1ull));
            if (slot < seg_cap) {
                const size_t p = (size_t)seg * seg_cap + slot;
                qf[p] = make_float4(zr.y, zi.y, cr.y, ci.y);
                qi[p] = p0 + 1;
            } else {
                float zrs = zr.y, zis = zi.y, as = 1.0f, cs = cnt1;
                iter_checks(cr.y, ci.y, zrs, zis, as, cs, 240);
                out[p0 + 1] = cs;
            }
        }
    }
    if (!s0) out[p0] = sc0 ? 256.0f : cnt0;
    if (has1 && !s1) out[p0 + 1] = sc1 ? 256.0f : cnt1;
}

// ---------- stage B, packed fixed-240, single dispatch ----------
// Pairs record k with k + ceil(nq/2): both streams coalesced.
__global__ __launch_bounds__(256) void mandel_stage_b_pk(
    float* __restrict__ out, const unsigned char* __restrict__ ws,
    unsigned seg_cap, int blocks_per_seg)
{
    const int seg = (int)(blockIdx.x & 63u);
    const int grp = (int)(blockIdx.x >> 6);
    const unsigned cnt_s = *(const unsigned*)(ws + (size_t)seg * 64u);
    const unsigned nq = (cnt_s < seg_cap) ? cnt_s : seg_cap;
    const unsigned half = (nq + 1u) >> 1;
    const unsigned stride = (unsigned)blocks_per_seg * 256u;
    const float4* qf = (const float4*)(ws + 4096);
    const int*    qi = (const int*)(ws + 4096 + (size_t)seg_cap * 64u * 16u);
    const size_t segbase = (size_t)seg * seg_cap;

    for (unsigned k = (unsigned)grp * 256u + threadIdx.x; k < half; k += stride) {
        const unsigned r1 = k + half;
        const bool v1 = (r1 < nq);
        const float4 rec0 = qf[segbase + k];
        const float4 rec1 = v1 ? qf[segbase + r1] : rec0;
        const int idx0 = qi[segbase + k];
        const int idx1 = v1 ? qi[segbase + r1] : -1;
        f32x2 zr; zr.x = rec0.x; zr.y = rec1.x;
        f32x2 zi; zi.x = rec0.y; zi.y = rec1.y;
        f32x2 cr; cr.x = rec0.z; cr.y = rec1.z;
        f32x2 ci; ci.x = rec0.w; ci.y = rec1.w;
        float act0 = 1.0f, act1 = v1 ? 1.0f : 0.0f;
        float cnt0 = 16.0f, cnt1 = 16.0f;
        iter_checks_pk(cr, ci, zr, zi, act0, act1, cnt0, cnt1, 240);
        out[idx0] = cnt0;
        if (v1) out[idx1] = cnt1;
    }
}

// ---------- proven scalar fallbacks (tiny ws only) ----------
__global__ __launch_bounds__(256) void mandel_mono(
    const float* __restrict__ c_real, const float* __restrict__ c_imag,
    float* __restrict__ out, int n)
{
    int i = blockIdx.x * blockDim.x + threadIdx.x;
    if (i >= n) return;
    const float cr = c_real[i], ci = c_imag[i];
    float zr = cr, zi = ci, act = 1.0f, cnt = 0.0f;
    iter_checks(cr, ci, zr, zi, act, cnt, MAX_ITERS);
    out[i] = cnt;
}

extern "C" void kernel_launch(void* const* d_in, const int* in_sizes, int n_in,
                              void* d_out, int out_size, void* d_ws, size_t ws_size,
                              hipStream_t stream)
{
    const float* c_real = (const float*)d_in[0];
    const float* c_imag = (const float*)d_in[1];
    float* out = (float*)d_out;
    const int n = in_sizes[0];  // 4096*4096
    const int block = 256;

    unsigned char* ws = (unsigned char*)d_ws;
    const size_t avail = (ws_size > 4096) ? (ws_size - 4096) : 0;
    const unsigned seg_cap = (unsigned)(avail / (64u * 20u));  // 20B/rec, 1 queue

    if (seg_cap < 8192u) {  // ws too small for compaction: proven fallback
        const int gridA = (n + block - 1) / block;
        mandel_mono<<<gridA, block, 0, stream>>>(c_real, c_imag, out, n);
        return;
    }

    zero_ctrs<<<1, 64, 0, stream>>>(ws);

    const int npairs = (n + 1) / 2;
    const int gridA = (npairs + block - 1) / block;
    mandel_stage_a_pk<<<gridA, block, 0, stream>>>(c_real, c_imag, out,
                                                   ws, seg_cap, n);
    // Single fixed-240 packed consumer: 64 segs x 64 blocks.
    const int bps = 64;
    mandel_stage_b_pk<<<64 * bps, block, 0, stream>>>(out, ws, seg_cap, bps);
}

// Round 6
// 237.623 us; speedup vs baseline: 1.0117x; 1.0117x over previous
//
#include <hip/hip_runtime.h>

// Mandelbrot counts — R6-proven bit-exact arithmetic + compaction + wave-
// aggregated enqueue (R8) + packed fp32 (R12/R13) + fused 6-op pk z-block
// with neg modifiers and 4px/lane dual-stream ILP (R14).
//
// R13 post-mortem: instr/wave ~538 == R12's 535 — the "fat reduction" didn't
// land; per check-pair ~18 slots emitted vs 14 intended (xors for -zi2 +
// asm-boundary copies). Still VALU-issue bound (HBM 26%, LDS 0).
// R14: (1) z-update fused into ONE asm block of exactly 6 v_pk_* ops,
// -zi2 via VOP3P neg_lo/neg_hi (sign-bit neg == proven neg-modifier
// semantics, exact); bookkeeping kept VERBATIM from the proven lineage
// (C ternary cmp/cndmask + add). Floor 12 slots/check-pair.
// (2) 4 px/lane = two independent f32x2 streams: in-wave ILP fills the
// pk dependency bubbles; wave count halves -> prologue/enqueue amortized.
// (3) same 3 dispatches: zero_ctrs + A + fixed-240 B. Enqueue = ONE leader
// atomicAdd per wave over 4 ballot masks (proven striped-64 counters).
//
// Exactness: per half, v_pk_{mul,fma,add}_f32 == scalar v_{mul,fma,add}_f32
// rounding (proven R12/R13); sequence per check unchanged:
//   zi2=fl(zi*zi); mag=fma(zr,zr,zi2); t=fma(zr,zr,-zi2);
//   zr'=fl(t+cr); t2=fl(zr+zr); zi'=fma(t2,zi,ci)
//   act=(mag<4)?act:0 (sticky, NaN-safe); cnt+=act (exact small-int add)
// absmax=0 lineage R6..R13. Cardioid/bulb shortcut margin 1e-3 (HW-valid).
//
// d_ws: [0,4096) 64 counter lines (64B apart, dword +0) | q float4 recs
// seg-major | int idx after. Overflow -> finish inline (correct, slower).
// Tiny ws -> proven scalar fallback.

#define MAX_ITERS 256

typedef __attribute__((ext_vector_type(2))) float f32x2;
typedef __attribute__((ext_vector_type(4))) float f32x4;

// ---------- scalar proven body (fallback + overflow inline) ----------
__device__ __forceinline__ float mul32(float a, float b) {
    float d; asm("v_mul_f32 %0, %1, %2" : "=v"(d) : "v"(a), "v"(b)); return d;
}
__device__ __forceinline__ float add32(float a, float b) {
    float d; asm("v_add_f32 %0, %1, %2" : "=v"(d) : "v"(a), "v"(b)); return d;
}
__device__ __forceinline__ float fma32(float a, float b, float c) {
    float d; asm("v_fma_f32 %0, %1, %2, %3" : "=v"(d) : "v"(a), "v"(b), "v"(c)); return d;
}
__device__ __forceinline__ float fma32_negc(float a, float b, float c) {
    float d; asm("v_fma_f32 %0, %1, %2, -%3" : "=v"(d) : "v"(a), "v"(b), "v"(c)); return d;
}

__device__ __forceinline__ void iter_checks(float cr, float ci,
                                            float& zr, float& zi,
                                            float& act, float& cnt, int nchecks)
{
    #pragma unroll 8
    for (int s = 0; s < nchecks; ++s) {
        const float zi2 = mul32(zi, zi);
        const float mag = fma32(zr, zr, zi2);
        act = (mag < 4.0f) ? act : 0.0f;
        cnt = cnt + act;
        const float t   = fma32_negc(zr, zr, zi2);
        const float nr  = add32(t, cr);
        const float t2  = add32(zr, zr);
        zi = fma32(t2, zi, ci);
        zr = nr;
    }
}

// ---------- fused packed z-step: exactly 6 v_pk ops, mag out ----------
__device__ __forceinline__ void zstep2(const f32x2 cr, const f32x2 ci,
                                       f32x2& zr, f32x2& zi, f32x2& mag)
{
    f32x2 s, t, u;
    asm("v_pk_mul_f32 %0, %5, %5\n\t"                                   // s   = zi*zi
        "v_pk_fma_f32 %1, %4, %4, %0\n\t"                               // mag = zr*zr + s
        "v_pk_fma_f32 %2, %4, %4, %0 neg_lo:[0,0,1] neg_hi:[0,0,1]\n\t" // t = zr*zr - s
        "v_pk_add_f32 %3, %4, %4\n\t"                                   // u   = zr + zr
        "v_pk_add_f32 %4, %2, %6\n\t"                                   // zr' = t + cr
        "v_pk_fma_f32 %5, %3, %5, %7"                                   // zi' = u*zi + ci
        : "=&v"(s), "=&v"(mag), "=&v"(t), "=&v"(u), "+v"(zr), "+v"(zi)
        : "v"(cr), "v"(ci));
}

// One check over 4 pixels (two streams). Bookkeeping is the PROVEN C form.
__device__ __forceinline__ void check4(
    const f32x2 crA, const f32x2 ciA, f32x2& zrA, f32x2& ziA,
    const f32x2 crB, const f32x2 ciB, f32x2& zrB, f32x2& ziB,
    float& act0, float& act1, float& act2, float& act3,
    float& cnt0, float& cnt1, float& cnt2, float& cnt3)
{
    f32x2 magA, magB;
    zstep2(crA, ciA, zrA, ziA, magA);
    zstep2(crB, ciB, zrB, ziB, magB);
    act0 = (magA.x < 4.0f) ? act0 : 0.0f;  cnt0 += act0;
    act1 = (magA.y < 4.0f) ? act1 : 0.0f;  cnt1 += act1;
    act2 = (magB.x < 4.0f) ? act2 : 0.0f;  cnt2 += act2;
    act3 = (magB.y < 4.0f) ? act3 : 0.0f;  cnt3 += act3;
}

__device__ __forceinline__ int lane_id() {
    return __builtin_amdgcn_mbcnt_hi(~0u, __builtin_amdgcn_mbcnt_lo(~0u, 0));
}

__device__ __forceinline__ bool in_shortcut(float cr, float ci) {
    const float xq = cr - 0.25f;
    const float q  = xq * xq + ci * ci;
    const bool in_card = (q * (q + xq) - 0.25f * ci * ci) < -1e-3f;
    const float xb = cr + 1.0f;
    const bool in_bulb = (xb * xb + ci * ci) < (0.0625f - 1e-3f);
    return in_card | in_bulb;
}

__global__ void zero_ctrs(unsigned char* ws) {
    if (threadIdx.x < 64)
        *(unsigned*)(ws + (size_t)threadIdx.x * 64u) = 0u;
}

// ---------- stage A: 4 pixels per thread, 16 checks ----------
__global__ __launch_bounds__(256) void mandel_stage_a_q(
    const float* __restrict__ c_real, const float* __restrict__ c_imag,
    float* __restrict__ out, unsigned char* __restrict__ ws,
    unsigned seg_cap, int n)
{
    const int tq = blockIdx.x * blockDim.x + threadIdx.x;
    const int p0 = tq << 2;
    if (p0 >= n) return;

    if (p0 + 3 >= n) {  // ragged tail (n%4!=0): finish fully inline, scalar
        for (int j = 0; j < 4 && p0 + j < n; ++j) {
            const float cr = c_real[p0 + j], ci = c_imag[p0 + j];
            if (in_shortcut(cr, ci)) { out[p0 + j] = 256.0f; continue; }
            float zr = cr, zi = ci, act = 1.0f, cnt = 0.0f;
            iter_checks(cr, ci, zr, zi, act, cnt, MAX_ITERS);
            out[p0 + j] = cnt;
        }
        return;
    }

    const f32x4 cr4 = *(const f32x4*)(c_real + p0);
    const f32x4 ci4 = *(const f32x4*)(c_imag + p0);
    const f32x2 crA = {cr4.x, cr4.y}, ciA = {ci4.x, ci4.y};
    const f32x2 crB = {cr4.z, cr4.w}, ciB = {ci4.z, ci4.w};
    const bool sc0 = in_shortcut(cr4.x, ci4.x);
    const bool sc1 = in_shortcut(cr4.y, ci4.y);
    const bool sc2 = in_shortcut(cr4.z, ci4.z);
    const bool sc3 = in_shortcut(cr4.w, ci4.w);

    f32x2 zrA = crA, ziA = ciA, zrB = crB, ziB = ciB;
    float act0 = 1.0f, act1 = 1.0f, act2 = 1.0f, act3 = 1.0f;
    float cnt0 = 0.0f, cnt1 = 0.0f, cnt2 = 0.0f, cnt3 = 0.0f;
    #pragma unroll
    for (int s = 0; s < 16; ++s)   // checks z_0..z_15
        check4(crA, ciA, zrA, ziA, crB, ciB, zrB, ziB,
               act0, act1, act2, act3, cnt0, cnt1, cnt2, cnt3);

    const bool sv0 = (!sc0) && (act0 != 0.0f);
    const bool sv1 = (!sc1) && (act1 != 0.0f);
    const bool sv2 = (!sc2) && (act2 != 0.0f);
    const bool sv3 = (!sc3) && (act3 != 0.0f);

    const unsigned long long m0 = __ballot(sv0);
    const unsigned long long m1 = __ballot(sv1);
    const unsigned long long m2 = __ballot(sv2);
    const unsigned long long m3 = __ballot(sv3);
    const unsigned long long any = m0 | m1 | m2 | m3;
    if (any != 0ull) {
        const int lane = lane_id();
        const int leader = (int)__ffsll(any) - 1;
        const int seg = blockIdx.x & 63;
        unsigned* ctr = (unsigned*)(ws + (size_t)seg * 64u);
        const unsigned c0 = (unsigned)__popcll(m0);
        const unsigned c1 = (unsigned)__popcll(m1);
        const unsigned c2 = (unsigned)__popcll(m2);
        const unsigned c3 = (unsigned)__popcll(m3);
        unsigned base = 0u;
        if (lane == leader) base = atomicAdd(ctr, c0 + c1 + c2 + c3);
        base = (unsigned)__shfl((int)base, leader, 64);
        float4* qf = (float4*)(ws + 4096);
        int*    qi = (int*)(ws + 4096 + (size_t)seg_cap * 64u * 16u);
        const unsigned long long below = (1ull << lane) - 1ull;
        const size_t segbase = (size_t)seg * seg_cap;
        const unsigned pre1 = c0, pre2 = c0 + c1, pre3 = c0 + c1 + c2;

        float zrv[4] = {zrA.x, zrA.y, zrB.x, zrB.y};
        float ziv[4] = {ziA.x, ziA.y, ziB.x, ziB.y};
        float crv[4] = {cr4.x, cr4.y, cr4.z, cr4.w};
        float civ[4] = {ci4.x, ci4.y, ci4.z, ci4.w};
        float cnv[4] = {cnt0, cnt1, cnt2, cnt3};
        const bool svv[4] = {sv0, sv1, sv2, sv3};
        const unsigned prev[4] = {0u, pre1, pre2, pre3};
        const unsigned long long mv[4] = {m0, m1, m2, m3};
        #pragma unroll
        for (int j = 0; j < 4; ++j) {
            if (!svv[j]) continue;
            const unsigned slot = base + prev[j] +
                (unsigned)__popcll(mv[j] & below);
            if (slot < seg_cap) {
                qf[segbase + slot] = make_float4(zrv[j], ziv[j], crv[j], civ[j]);
                qi[segbase + slot] = p0 + j;
            } else {   // overflow: finish inline with proven scalar body
                float zrs = zrv[j], zis = ziv[j], as = 1.0f, cs = cnv[j];
                iter_checks(crv[j], civ[j], zrs, zis, as, cs, 240);
                out[p0 + j] = cs;
            }
        }
    }
    if (!sv0) out[p0 + 0] = sc0 ? 256.0f : cnt0;
    if (!sv1) out[p0 + 1] = sc1 ? 256.0f : cnt1;
    if (!sv2) out[p0 + 2] = sc2 ? 256.0f : cnt2;
    if (!sv3) out[p0 + 3] = sc3 ? 256.0f : cnt3;
}

// ---------- stage B: 4 records per thread, fixed 240 checks ----------
// Record k paired with k+q, k+2q, k+3q (q = ceil(nq/4)): all streams coalesced.
__global__ __launch_bounds__(256) void mandel_stage_b_q(
    float* __restrict__ out, const unsigned char* __restrict__ ws,
    unsigned seg_cap, int blocks_per_seg)
{
    const int seg = (int)(blockIdx.x & 63u);
    const int grp = (int)(blockIdx.x >> 6);
    const unsigned cnt_s = *(const unsigned*)(ws + (size_t)seg * 64u);
    const unsigned nq = (cnt_s < seg_cap) ? cnt_s : seg_cap;
    const unsigned q = (nq + 3u) >> 2;
    const unsigned stride = (unsigned)blocks_per_seg * 256u;
    const float4* qf = (const float4*)(ws + 4096);
    const int*    qi = (const int*)(ws + 4096 + (size_t)seg_cap * 64u * 16u);
    const size_t segbase = (size_t)seg * seg_cap;

    for (unsigned k = (unsigned)grp * 256u + threadIdx.x; k < q; k += stride) {
        const unsigned i1 = k + q, i2 = k + 2u * q, i3 = k + 3u * q;
        const bool v1 = (i1 < nq), v2 = (i2 < nq), v3 = (i3 < nq);
        const float4 r0 = qf[segbase + k];
        const float4 r1 = v1 ? qf[segbase + i1] : r0;
        const float4 r2 = v2 ? qf[segbase + i2] : r0;
        const float4 r3 = v3 ? qf[segbase + i3] : r0;
        const int idx0 = qi[segbase + k];
        const int idx1 = v1 ? qi[segbase + i1] : -1;
        const int idx2 = v2 ? qi[segbase + i2] : -1;
        const int idx3 = v3 ? qi[segbase + i3] : -1;

        f32x2 zrA = {r0.x, r1.x}, ziA = {r0.y, r1.y};
        f32x2 crA = {r0.z, r1.z}, ciA = {r0.w, r1.w};
        f32x2 zrB = {r2.x, r3.x}, ziB = {r2.y, r3.y};
        f32x2 crB = {r2.z, r3.z}, ciB = {r2.w, r3.w};
        float act0 = 1.0f, act1 = v1 ? 1.0f : 0.0f;
        float act2 = v2 ? 1.0f : 0.0f, act3 = v3 ? 1.0f : 0.0f;
        float cnt0 = 16.0f, cnt1 = 16.0f, cnt2 = 16.0f, cnt3 = 16.0f;
        #pragma unroll 8
        for (int s = 0; s < 240; ++s)    // checks z_16..z_255
            check4(crA, ciA, zrA, ziA, crB, ciB, zrB, ziB,
                   act0, act1, act2, act3, cnt0, cnt1, cnt2, cnt3);
        out[idx0] = cnt0;
        if (v1) out[idx1] = cnt1;
        if (v2) out[idx2] = cnt2;
        if (v3) out[idx3] = cnt3;
    }
}

// ---------- proven scalar fallback (tiny ws only) ----------
__global__ __launch_bounds__(256) void mandel_mono(
    const float* __restrict__ c_real, const float* __restrict__ c_imag,
    float* __restrict__ out, int n)
{
    int i = blockIdx.x * blockDim.x + threadIdx.x;
    if (i >= n) return;
    const float cr = c_real[i], ci = c_imag[i];
    float zr = cr, zi = ci, act = 1.0f, cnt = 0.0f;
    iter_checks(cr, ci, zr, zi, act, cnt, MAX_ITERS);
    out[i] = cnt;
}

extern "C" void kernel_launch(void* const* d_in, const int* in_sizes, int n_in,
                              void* d_out, int out_size, void* d_ws, size_t ws_size,
                              hipStream_t stream)
{
    const float* c_real = (const float*)d_in[0];
    const float* c_imag = (const float*)d_in[1];
    float* out = (float*)d_out;
    const int n = in_sizes[0];  // 4096*4096
    const int block = 256;

    unsigned char* ws = (unsigned char*)d_ws;
    const size_t avail = (ws_size > 4096) ? (ws_size - 4096) : 0;
    const unsigned seg_cap = (unsigned)(avail / (64u * 20u));  // 20B/rec

    if (seg_cap < 8192u) {  // ws too small for compaction: proven fallback
        const int gridA = (n + block - 1) / block;
        mandel_mono<<<gridA, block, 0, stream>>>(c_real, c_imag, out, n);
        return;
    }

    zero_ctrs<<<1, 64, 0, stream>>>(ws);

    const int nquads = (n + 3) / 4;
    const int gridA = (nquads + block - 1) / block;
    mandel_stage_a_q<<<gridA, block, 0, stream>>>(c_real, c_imag, out,
                                                  ws, seg_cap, n);
    // Fixed-240 consumer: 64 segs x 32 blocks, 4 records/thread.
    const int bps = 32;
    mandel_stage_b_q<<<64 * bps, block, 0, stream>>>(out, ws, seg_cap, bps);
}